// Round 2
// baseline (13153.282 us; speedup 1.0000x reference)
//
#include <hip/hip_runtime.h>
#include <hip/hip_bf16.h>

typedef __bf16 bf16x8 __attribute__((ext_vector_type(8)));
typedef float floatx4 __attribute__((ext_vector_type(4)));

// ---------------- prep kernels ----------------

// x (65536,100) fp32 -> Xb (65536,128) bf16, zero-padded cols 100..127
__global__ __launch_bounds__(256) void prep_x(const float* __restrict__ x,
                                              __hip_bfloat16* __restrict__ Xb) {
    int i = blockIdx.x * 256 + threadIdx.x;          // 0 .. 65536*128-1
    int row = i >> 7, k = i & 127;
    float v = (k < 100) ? x[row * 100 + k] : 0.f;
    Xb[i] = __float2bfloat16(v);
}

// zero slot 0 of H0b, H1b (bf16 256x384) and the barrier counters
__global__ __launch_bounds__(256) void init_zero(__hip_bfloat16* __restrict__ H0b,
                                                 __hip_bfloat16* __restrict__ H1b,
                                                 unsigned* __restrict__ bar) {
    int i = blockIdx.x * 256 + threadIdx.x;          // 0..98303
    __hip_bfloat16 z = __float2bfloat16(0.f);
    H0b[i] = z; H1b[i] = z;
    if (i < 512) bar[i] = 0u;
}

// Wtmp (10,512) = W3 (10,1024) @ W2 (1024,512)
__global__ __launch_bounds__(256) void wtmp_k(const float* __restrict__ W3,
                                              const float* __restrict__ W2,
                                              float* __restrict__ Wtmp) {
    int idx = blockIdx.x * 256 + threadIdx.x;        // 0..5119
    int j = idx / 512, i = idx % 512;
    float acc = 0.f;
    for (int q = 0; q < 1024; q++) acc += W3[j * 1024 + q] * W2[q * 512 + i];
    Wtmp[idx] = acc;
}

// Weff (10,384) = Wtmp (10,512) @ W1 (512,384)
__global__ __launch_bounds__(256) void weff_k(const float* __restrict__ Wtmp,
                                              const float* __restrict__ W1,
                                              float* __restrict__ Weff) {
    int idx = blockIdx.x * 256 + threadIdx.x;        // 0..3839
    if (idx >= 3840) return;
    int j = idx / 384, i = idx % 384;
    float acc = 0.f;
    for (int q = 0; q < 512; q++) acc += Wtmp[j * 512 + q] * W1[q * 384 + i];
    Weff[idx] = acc;
}

// beff (10) = b3 + W3@b2 + Wtmp@b1
__global__ void beff_k(const float* __restrict__ W3, const float* __restrict__ b2,
                       const float* __restrict__ Wtmp, const float* __restrict__ b1,
                       const float* __restrict__ b3, float* __restrict__ beff) {
    int j = threadIdx.x;
    if (j >= 10) return;
    float acc = b3[j];
    for (int q = 0; q < 1024; q++) acc += W3[j * 1024 + q] * b2[q];
    for (int q = 0; q < 512; q++)  acc += Wtmp[j * 512 + q] * b1[q];
    beff[j] = acc;
}

// ---------------- persistent LSTM (both layers) ----------------
// 192 blocks = 8 batch-groups (g = blockIdx&7, 32 rows each) x 24 n-blocks
// (bsub = blockIdx>>3, d-slice [16*bsub,16*bsub+16) across 4 gates).
// Wave w handles gate w. Weights register-resident (B-frags fixed per phase).
// Per-step group barrier: threadfence + atomic counter (agent scope).

__device__ __forceinline__ void group_barrier(unsigned* ctr, unsigned target, int tid) {
    __threadfence();       // each wave drains its own stores, agent visibility
    __syncthreads();
    if (tid == 0) {
        __hip_atomic_fetch_add(ctr, 1u, __ATOMIC_RELEASE, __HIP_MEMORY_SCOPE_AGENT);
        while (__hip_atomic_load(ctr, __ATOMIC_ACQUIRE, __HIP_MEMORY_SCOPE_AGENT) < target) {}
    }
    __syncthreads();
}

template<int KIN, int K1, int LDA1>
__device__ __forceinline__ void run_layer(
    const float* __restrict__ Wih, const float* __restrict__ Whh,
    const float* __restrict__ bihp, const float* __restrict__ bhhp,
    const __hip_bfloat16* __restrict__ A1base, int a1slot0,
    __hip_bfloat16* __restrict__ H,          // own hidden buffer, slots 0..256
    float* gbuf, unsigned* ctr, unsigned& target,
    int g, int bsub, int tid)
{
    constexpr int NK1 = K1 / 32;
    constexpr int NK = NK1 + 12;
    int lane = tid & 63, wv = tid >> 6;
    int koff = (lane >> 4) * 8;
    int nrow = wv * 384 + bsub * 16 + (lane & 15);

    // ---- load weight fragments into registers (once per phase) ----
    bf16x8 bfrag[NK];
#pragma unroll
    for (int kk = 0; kk < NK; kk++) {
        bf16x8 f;
#pragma unroll
        for (int j = 0; j < 8; j++) {
            int kglob = kk * 32 + koff + j;
            float v;
            if (kglob < K1) v = (kglob < KIN) ? Wih[(size_t)nrow * KIN + kglob] : 0.f;
            else            v = Whh[(size_t)nrow * 384 + (kglob - K1)];
            f[j] = (__bf16)v;
        }
        bfrag[kk] = f;
    }

    // ---- cell-thread state (fixed (m,d) per thread) ----
    int e2 = tid * 2, mcell = e2 >> 4, d0 = e2 & 15;   // d0 even
    int dg = bsub * 16 + d0;
    float bI0 = bihp[dg] + bhhp[dg],               bI1 = bihp[dg+1] + bhhp[dg+1];
    float bF0 = bihp[384+dg] + bhhp[384+dg],       bF1 = bihp[385+dg] + bhhp[385+dg];
    float bG0 = bihp[768+dg] + bhhp[768+dg],       bG1 = bihp[769+dg] + bhhp[769+dg];
    float bO0 = bihp[1152+dg] + bhhp[1152+dg],     bO1 = bihp[1153+dg] + bhhp[1153+dg];
    float c0 = 0.f, c1 = 0.f;

    int mrow = g * 32 + (lane & 15);
    int r0 = (lane >> 4) * 4, ccol = lane & 15;
    __hip_bfloat16* hout_base = H + (size_t)(g * 32 + mcell) * 384 + dg;

#pragma unroll 1
    for (int t = 0; t < 256; t++) {
        const __hip_bfloat16* A1p = A1base + (size_t)(t + a1slot0) * 256 * LDA1 + (size_t)mrow * LDA1;
        const __hip_bfloat16* Hp  = H + (size_t)t * 98304 + (size_t)mrow * 384;
        floatx4 acc0 = {0.f,0.f,0.f,0.f}, acc1 = {0.f,0.f,0.f,0.f};
#pragma unroll
        for (int kk = 0; kk < NK1; kk++) {
            bf16x8 a0 = *reinterpret_cast<const bf16x8*>(A1p + kk * 32 + koff);
            bf16x8 a1 = *reinterpret_cast<const bf16x8*>(A1p + 16 * LDA1 + kk * 32 + koff);
            acc0 = __builtin_amdgcn_mfma_f32_16x16x32_bf16(a0, bfrag[kk], acc0, 0, 0, 0);
            acc1 = __builtin_amdgcn_mfma_f32_16x16x32_bf16(a1, bfrag[kk], acc1, 0, 0, 0);
        }
#pragma unroll
        for (int kk = 0; kk < 12; kk++) {
            bf16x8 a0 = *reinterpret_cast<const bf16x8*>(Hp + kk * 32 + koff);
            bf16x8 a1 = *reinterpret_cast<const bf16x8*>(Hp + 16 * 384 + kk * 32 + koff);
            acc0 = __builtin_amdgcn_mfma_f32_16x16x32_bf16(a0, bfrag[NK1 + kk], acc0, 0, 0, 0);
            acc1 = __builtin_amdgcn_mfma_f32_16x16x32_bf16(a1, bfrag[NK1 + kk], acc1, 0, 0, 0);
        }
        // C layout: col=lane&15, row=(lane>>4)*4+r ; gbuf[gate][m 0..31][18]
#pragma unroll
        for (int r = 0; r < 4; r++) {
            gbuf[((wv << 5) + r0 + r) * 18 + ccol]      = acc0[r];
            gbuf[((wv << 5) + 16 + r0 + r) * 18 + ccol] = acc1[r];
        }
        __syncthreads();

        float gi0 = gbuf[(     mcell) * 18 + d0]     + bI0;
        float gi1 = gbuf[(     mcell) * 18 + d0 + 1] + bI1;
        float gf0 = gbuf[(32 + mcell) * 18 + d0]     + bF0;
        float gf1 = gbuf[(32 + mcell) * 18 + d0 + 1] + bF1;
        float gg0 = gbuf[(64 + mcell) * 18 + d0]     + bG0;
        float gg1 = gbuf[(64 + mcell) * 18 + d0 + 1] + bG1;
        float go0 = gbuf[(96 + mcell) * 18 + d0]     + bO0;
        float go1 = gbuf[(96 + mcell) * 18 + d0 + 1] + bO1;
        float i0 = 1.f / (1.f + __expf(-gi0)), i1 = 1.f / (1.f + __expf(-gi1));
        float f0 = 1.f / (1.f + __expf(-gf0)), f1 = 1.f / (1.f + __expf(-gf1));
        float z0 = tanhf(gg0), z1 = tanhf(gg1);
        float o0 = 1.f / (1.f + __expf(-go0)), o1 = 1.f / (1.f + __expf(-go1));
        c0 = f0 * c0 + i0 * z0;
        c1 = f1 * c1 + i1 * z1;
        float h0 = o0 * tanhf(c0), h1 = o1 * tanhf(c1);

        __hip_bfloat162 hv;
        hv.x = __float2bfloat16(h0);
        hv.y = __float2bfloat16(h1);
        *reinterpret_cast<__hip_bfloat162*>(hout_base + (size_t)(t + 1) * 98304) = hv;

        target += 24;
        group_barrier(ctr, target, tid);
    }
}

__global__ __launch_bounds__(256, 1) void lstm_persistent(
    const __hip_bfloat16* __restrict__ Xb,
    const float* __restrict__ Wih0, const float* __restrict__ Whh0,
    const float* __restrict__ bih0, const float* __restrict__ bhh0,
    const float* __restrict__ Wih1, const float* __restrict__ Whh1,
    const float* __restrict__ bih1, const float* __restrict__ bhh1,
    __hip_bfloat16* __restrict__ H0, __hip_bfloat16* __restrict__ H1,
    unsigned* __restrict__ bar)
{
    __shared__ float gbuf[4 * 32 * 18];
    int tid = threadIdx.x;
    int g = blockIdx.x & 7;        // group likely maps to one XCD (round-robin)
    int bsub = blockIdx.x >> 3;    // 0..23
    unsigned target = 0;
    unsigned* ctr = bar + g * 64;  // 256B-spaced counters
    // layer 0: A1 = Xb slot t (lda 128), own H = H0
    run_layer<100, 128, 128>(Wih0, Whh0, bih0, bhh0, Xb, 0, H0, gbuf, ctr, target, g, bsub, tid);
    // layer 1: A1 = H0 slot t+1 (lda 384), own H = H1
    run_layer<384, 384, 384>(Wih1, Whh1, bih1, bhh1, H0, 1, H1, gbuf, ctr, target, g, bsub, tid);
}

// ---------------- emissions: EM (65536,10) = H1 (65536,384) @ Weff^T + beff ----------------
__global__ __launch_bounds__(256) void em_kernel(const __hip_bfloat16* __restrict__ H1,
                                                 const float* __restrict__ Weff,
                                                 const float* __restrict__ beff,
                                                 float* __restrict__ em) {
    __shared__ __hip_bfloat16 At[256 * 68];
    __shared__ float Wt[640];
    __shared__ float bf[10];
    int tid = threadIdx.x;
    int row0 = blockIdx.x * 256;
    if (tid < 10) bf[tid] = beff[tid];
    float acc[10];
#pragma unroll
    for (int j = 0; j < 10; j++) acc[j] = 0.f;

    for (int kt = 0; kt < 384; kt += 64) {
        __syncthreads();
#pragma unroll
        for (int q = 0; q < 16; q++) {
            int flat = q * 256 + tid;
            int r = flat >> 4;
            int k4 = flat & 15;
            const __hip_bfloat16* src = H1 + (size_t)(row0 + r) * 384 + kt + k4 * 4;
            *reinterpret_cast<uint2*>(&At[r * 68 + k4 * 4]) =
                *reinterpret_cast<const uint2*>(src);
        }
        for (int q = tid; q < 640; q += 256) {
            int j = q >> 6, k = q & 63;
            Wt[q] = Weff[j * 384 + kt + k];
        }
        __syncthreads();
        for (int k = 0; k < 64; k++) {
            float a = __bfloat162float(At[tid * 68 + k]);
#pragma unroll
            for (int j = 0; j < 10; j++) acc[j] += a * Wt[j * 64 + k];
        }
    }
#pragma unroll
    for (int j = 0; j < 10; j++) em[(size_t)(row0 + tid) * 10 + j] = acc[j] + bf[j];
}

// ---------------- CRF: one block (64 thr) per sequence ----------------
__global__ __launch_bounds__(64) void crf_kernel(const float* __restrict__ em,
                                                 const int* __restrict__ tags,
                                                 const float* __restrict__ start_t,
                                                 const float* __restrict__ end_t,
                                                 const float* __restrict__ trans,
                                                 float* __restrict__ nll) {
    int s = blockIdx.x;
    int l = threadIdx.x;
    __shared__ float tr[100];
    __shared__ float aA[16], aB[16];
    if (l < 100) tr[l] = trans[l];
    if (l < 36)  tr[l + 64] = trans[l + 64];
    __syncthreads();

    float part = 0.f;
    for (int b = l; b < 256; b += 64) {
        int tg = tags[s * 256 + b];
        part += em[(size_t)(s * 256 + b) * 10 + tg];
        if (b > 0) {
            int tp = tags[s * 256 + b - 1];
            part += tr[tp * 10 + tg];
        }
    }
    for (int off = 32; off > 0; off >>= 1) part += __shfl_down(part, off);

    if (l < 10) aA[l] = start_t[l] + em[(size_t)(s * 256) * 10 + l];
    __syncthreads();
    for (int b = 1; b < 256; b++) {
        const float* rb = (b & 1) ? aA : aB;
        float* wb = (b & 1) ? aB : aA;
        if (l < 10) {
            float m = -1e30f;
            for (int i = 0; i < 10; i++) m = fmaxf(m, rb[i] + tr[i * 10 + l]);
            float ssum = 0.f;
            for (int i = 0; i < 10; i++) ssum += __expf(rb[i] + tr[i * 10 + l] - m);
            wb[l] = em[(size_t)(s * 256 + b) * 10 + l] + m + __logf(ssum);
        }
        __syncthreads();
    }
    if (l == 0) {
        const float* af = aB;
        float m = -1e30f;
        for (int i = 0; i < 10; i++) m = fmaxf(m, af[i] + end_t[i]);
        float ssum = 0.f;
        for (int i = 0; i < 10; i++) ssum += __expf(af[i] + end_t[i] - m);
        float logZ = m + __logf(ssum);
        float score = part + start_t[tags[s * 256]] + end_t[tags[s * 256 + 255]];
        nll[s] = logZ - score;
    }
}

__global__ __launch_bounds__(256) void reduce_k(const float* __restrict__ nll,
                                                float* __restrict__ out) {
    __shared__ float sm[256];
    int t = threadIdx.x;
    sm[t] = nll[t];
    __syncthreads();
    for (int s = 128; s > 0; s >>= 1) {
        if (t < s) sm[t] += sm[t + s];
        __syncthreads();
    }
    if (t == 0) out[0] = sm[0];
}

// ---------------- host ----------------

extern "C" void kernel_launch(void* const* d_in, const int* in_sizes, int n_in,
                              void* d_out, int out_size, void* d_ws, size_t ws_size,
                              hipStream_t stream) {
    const float* x     = (const float*)d_in[0];
    const int*   tags  = (const int*)d_in[2];
    const float* Wih0  = (const float*)d_in[3];
    const float* Whh0  = (const float*)d_in[4];
    const float* bih0  = (const float*)d_in[5];
    const float* bhh0  = (const float*)d_in[6];
    const float* Wih1  = (const float*)d_in[7];
    const float* Whh1  = (const float*)d_in[8];
    const float* bih1  = (const float*)d_in[9];
    const float* bhh1  = (const float*)d_in[10];
    const float* W1    = (const float*)d_in[11];
    const float* b1    = (const float*)d_in[12];
    const float* W2    = (const float*)d_in[13];
    const float* b2    = (const float*)d_in[14];
    const float* W3    = (const float*)d_in[15];
    const float* b3    = (const float*)d_in[16];
    const float* start_t = (const float*)d_in[17];
    const float* end_t   = (const float*)d_in[18];
    const float* trans   = (const float*)d_in[19];

    char* ws = (char*)d_ws;
    size_t off = 0;
    auto alloc = [&](size_t bytes) { void* p = ws + off; off += (bytes + 255) & ~(size_t)255; return p; };

    __hip_bfloat16* Xb  = (__hip_bfloat16*)alloc((size_t)65536 * 128 * 2);
    __hip_bfloat16* H0b = (__hip_bfloat16*)alloc((size_t)257 * 98304 * 2);
    __hip_bfloat16* H1b = (__hip_bfloat16*)alloc((size_t)257 * 98304 * 2);
    float* EM   = (float*)alloc((size_t)65536 * 10 * 4);
    float* Wtmp = (float*)alloc((size_t)10 * 512 * 4);
    float* Weff = (float*)alloc((size_t)10 * 384 * 4);
    float* beff = (float*)alloc(256);
    float* nll  = (float*)alloc(256 * 4);
    unsigned* bar = (unsigned*)alloc(512 * 4);

    // prep (independent of each other)
    prep_x<<<32768, 256, 0, stream>>>(x, Xb);
    init_zero<<<384, 256, 0, stream>>>(H0b, H1b, bar);
    wtmp_k<<<20, 256, 0, stream>>>(W3, W2, Wtmp);
    weff_k<<<15, 256, 0, stream>>>(Wtmp, W1, Weff);
    beff_k<<<1, 64, 0, stream>>>(W3, b2, Wtmp, b1, b3, beff);

    // both LSTM layers in one persistent kernel
    lstm_persistent<<<192, 256, 0, stream>>>(Xb, Wih0, Whh0, bih0, bhh0,
                                             Wih1, Whh1, bih1, bhh1,
                                             H0b, H1b, bar);

    // emissions + CRF
    em_kernel<<<256, 256, 0, stream>>>(H1b + 98304, Weff, beff, EM);
    crf_kernel<<<256, 64, 0, stream>>>(EM, tags, start_t, end_t, trans, nll);
    reduce_k<<<1, 256, 0, stream>>>(nll, (float*)d_out);
}

// Round 3
// 2653.271 us; speedup vs baseline: 4.9574x; 4.9574x over previous
//
#include <hip/hip_runtime.h>
#include <hip/hip_bf16.h>

typedef __bf16 bf16x8 __attribute__((ext_vector_type(8)));
typedef __bf16 bf16x4 __attribute__((ext_vector_type(4)));
typedef float floatx4 __attribute__((ext_vector_type(4)));
typedef unsigned long long ull;

#define AGT __HIP_MEMORY_SCOPE_AGENT

__device__ __forceinline__ ull cload(const ull* p) {
    return __hip_atomic_load(const_cast<ull*>(p), __ATOMIC_RELAXED, AGT);
}
__device__ __forceinline__ void cstore(ull* p, ull v) {
    __hip_atomic_store(p, v, __ATOMIC_RELAXED, AGT);
}
__device__ __forceinline__ float fsig(float x) { return 1.f / (1.f + __expf(-x)); }
__device__ __forceinline__ float ftanh(float x) { return 1.f - 2.f / (__expf(2.f * x) + 1.f); }

// ---------------- prep kernels ----------------

// x (65536,100) fp32 -> Xb (65536,128) bf16, zero-padded cols 100..127
__global__ __launch_bounds__(256) void prep_x(const float* __restrict__ x,
                                              __hip_bfloat16* __restrict__ Xb) {
    int i = blockIdx.x * 256 + threadIdx.x;
    int row = i >> 7, k = i & 127;
    float v = (k < 100) ? x[row * 100 + k] : 0.f;
    Xb[i] = __float2bfloat16(v);
}

// Wcat (1536 x ldW) bf16 = [Wih (padded to K1) | Whh(1536x384)]
__global__ __launch_bounds__(256) void prep_wcat(const float* __restrict__ Wih, int Kin, int K1,
                                                 const float* __restrict__ Whh,
                                                 __hip_bfloat16* __restrict__ Wcat, int ldW) {
    int k = blockIdx.x * 256 + threadIdx.x;
    int row = blockIdx.y;
    if (k >= ldW) return;
    float v;
    if (k < K1) v = (k < Kin) ? Wih[row * Kin + k] : 0.f;
    else        v = Whh[row * 384 + (k - K1)];
    Wcat[row * ldW + k] = __float2bfloat16(v);
}

// zero slot 0 of H0b, H1b (bf16 256x384) and the barrier counters
__global__ __launch_bounds__(256) void init_zero(__hip_bfloat16* __restrict__ H0b,
                                                 __hip_bfloat16* __restrict__ H1b,
                                                 unsigned* __restrict__ bar) {
    int i = blockIdx.x * 256 + threadIdx.x;          // 0..98303
    __hip_bfloat16 z = __float2bfloat16(0.f);
    H0b[i] = z; H1b[i] = z;
    if (i < 1024) bar[i] = 0u;
}

// Wtmp (10,512) = W3 (10,1024) @ W2 (1024,512)
__global__ __launch_bounds__(256) void wtmp_k(const float* __restrict__ W3,
                                              const float* __restrict__ W2,
                                              float* __restrict__ Wtmp) {
    int idx = blockIdx.x * 256 + threadIdx.x;
    int j = idx / 512, i = idx % 512;
    float acc = 0.f;
    for (int q = 0; q < 1024; q++) acc += W3[j * 1024 + q] * W2[q * 512 + i];
    Wtmp[idx] = acc;
}

// Weff (10,384) = Wtmp (10,512) @ W1 (512,384)
__global__ __launch_bounds__(256) void weff_k(const float* __restrict__ Wtmp,
                                              const float* __restrict__ W1,
                                              float* __restrict__ Weff) {
    int idx = blockIdx.x * 256 + threadIdx.x;
    if (idx >= 3840) return;
    int j = idx / 384, i = idx % 384;
    float acc = 0.f;
    for (int q = 0; q < 512; q++) acc += Wtmp[j * 512 + q] * W1[q * 384 + i];
    Weff[idx] = acc;
}

// beff (10) = b3 + W3@b2 + Wtmp@b1
__global__ void beff_k(const float* __restrict__ W3, const float* __restrict__ b2,
                       const float* __restrict__ Wtmp, const float* __restrict__ b1,
                       const float* __restrict__ b3, float* __restrict__ beff) {
    int j = threadIdx.x;
    if (j >= 10) return;
    float acc = b3[j];
    for (int q = 0; q < 1024; q++) acc += W3[j * 1024 + q] * b2[q];
    for (int q = 0; q < 512; q++)  acc += Wtmp[j * 512 + q] * b1[q];
    beff[j] = acc;
}

// ---------------- persistent pipelined LSTM ----------------
// 192 blocks = 16 chains (8 batch-groups x 2 layers) x 12 gate-blocks.
// chain c = blockIdx&15: l = c&1, g = c>>1; bsub = blockIdx>>4 (0..11).
// Group g owns batch rows [g*32, g*32+32). Block bsub owns gate d-slice
// [bsub*32, bsub*32+32) across all 4 gates (wave = gate, 2 n-tiles/wave).
// Weights register-resident bf16 frags. All H traffic via relaxed agent
// atomics (sc0 sc1 -> coherent L3); NO fences, NO cache-wide maintenance.
// Layer1 chain g trails layer0 chain g by one step (producer counter).

__device__ __forceinline__ bf16x8 lds_frag(const short* As, int r, int k) {
    const short* p = As + r * 388 + k;
    bf16x4 lo = *reinterpret_cast<const bf16x4*>(p);
    bf16x4 hi = *reinterpret_cast<const bf16x4*>(p + 4);
    return __builtin_shufflevector(lo, hi, 0, 1, 2, 3, 4, 5, 6, 7);
}

// stage 32 rows x 384 bf16 (contiguous 24576B) into LDS (row stride 388)
__device__ __forceinline__ void stage(short* As, const ull* src, int tid) {
#pragma unroll
    for (int i = 0; i < 12; i++) {
        int q = tid + 256 * i;          // 0..3071  (96 ull per row)
        int row = q / 96;
        int c8 = q - row * 96;
        ull v = cload(src + q);
        *reinterpret_cast<ull*>(As + row * 388 + c8 * 4) = v;
    }
}

template<int L>
__device__ __forceinline__ void run_chain(
    const __hip_bfloat16* __restrict__ Xb,
    const __hip_bfloat16* __restrict__ Wcat,
    const float* __restrict__ bih, const float* __restrict__ bhh,
    const __hip_bfloat16* __restrict__ Hin,   // L=1: producer's H0
    __hip_bfloat16* __restrict__ Hown,
    unsigned* own, unsigned* prod,
    short* As1, short* As2, float* gbuf,
    int g, int bsub, int tid)
{
    constexpr int NKI = (L ? 12 : 4);       // input-K frags
    constexpr int NK  = NKI + 12;           // + recurrent
    constexpr int LDW = (L ? 768 : 512);
    int lane = tid & 63, wv = tid >> 6;
    int lane15 = lane & 15;
    int koff = (lane >> 4) * 8;

    // ---- register-resident weight fragments (plain bf16 vector loads) ----
    bf16x8 bf[2][NK];
#pragma unroll
    for (int nt = 0; nt < 2; nt++) {
        const __hip_bfloat16* Wrow =
            Wcat + (size_t)(wv * 384 + bsub * 32 + nt * 16 + lane15) * LDW;
#pragma unroll
        for (int kk = 0; kk < NK; kk++)
            bf[nt][kk] = *reinterpret_cast<const bf16x8*>(Wrow + kk * 32 + koff);
    }

    // ---- cell state: thread owns (m = tid>>3, d0 = (tid&7)*4 .. +3) ----
    int m = tid >> 3, d0 = (tid & 7) * 4;
    int dgl = bsub * 32 + d0;
    float bb[4][4];
#pragma unroll
    for (int j = 0; j < 4; j++)
#pragma unroll
        for (int jj = 0; jj < 4; jj++)
            bb[j][jj] = bih[j * 384 + dgl + jj] + bhh[j * 384 + dgl + jj];
    float cst[4] = {0.f, 0.f, 0.f, 0.f};

    const __hip_bfloat16* XbRow =
        (L == 0) ? (Xb + (size_t)(g * 32 + lane15) * 128 + koff) : nullptr;

#pragma unroll 1
    for (int t = 0; t < 256; t++) {
        // ---- wait: own chain done step t-1; producer done step t ----
        if (tid == 0) {
            unsigned lim = 12u * t;
            while (__hip_atomic_load(own, __ATOMIC_RELAXED, AGT) < lim) {}
            if (L == 1) {
                unsigned plim = 12u * (t + 1);
                while (__hip_atomic_load(prod, __ATOMIC_RELAXED, AGT) < plim) {}
            }
        }
        __syncthreads();
        asm volatile("" ::: "memory");

        // ---- stage h slices into LDS (coherent 8B loads) ----
        if (L == 1)
            stage(As1, reinterpret_cast<const ull*>(Hin + (size_t)(t + 1) * 98304 + g * 12288), tid);
        stage(As2, reinterpret_cast<const ull*>(Hown + (size_t)t * 98304 + g * 12288), tid);
        __syncthreads();

        // ---- MFMA ----
        floatx4 acc[2][2];
#pragma unroll
        for (int mt = 0; mt < 2; mt++)
#pragma unroll
            for (int nt = 0; nt < 2; nt++) acc[mt][nt] = floatx4{0.f, 0.f, 0.f, 0.f};

        if (L == 0) {
            const __hip_bfloat16* A1p = XbRow + (size_t)t * 32768;
#pragma unroll
            for (int kk = 0; kk < 4; kk++)
#pragma unroll
                for (int mt = 0; mt < 2; mt++) {
                    bf16x8 a = *reinterpret_cast<const bf16x8*>(A1p + mt * 2048 + kk * 32);
                    acc[mt][0] = __builtin_amdgcn_mfma_f32_16x16x32_bf16(a, bf[0][kk], acc[mt][0], 0, 0, 0);
                    acc[mt][1] = __builtin_amdgcn_mfma_f32_16x16x32_bf16(a, bf[1][kk], acc[mt][1], 0, 0, 0);
                }
        } else {
#pragma unroll
            for (int kk = 0; kk < 12; kk++)
#pragma unroll
                for (int mt = 0; mt < 2; mt++) {
                    bf16x8 a = lds_frag(As1, mt * 16 + lane15, kk * 32 + koff);
                    acc[mt][0] = __builtin_amdgcn_mfma_f32_16x16x32_bf16(a, bf[0][kk], acc[mt][0], 0, 0, 0);
                    acc[mt][1] = __builtin_amdgcn_mfma_f32_16x16x32_bf16(a, bf[1][kk], acc[mt][1], 0, 0, 0);
                }
        }
#pragma unroll
        for (int kk = 0; kk < 12; kk++)
#pragma unroll
            for (int mt = 0; mt < 2; mt++) {
                bf16x8 a = lds_frag(As2, mt * 16 + lane15, kk * 32 + koff);
                acc[mt][0] = __builtin_amdgcn_mfma_f32_16x16x32_bf16(a, bf[0][NKI + kk], acc[mt][0], 0, 0, 0);
                acc[mt][1] = __builtin_amdgcn_mfma_f32_16x16x32_bf16(a, bf[1][NKI + kk], acc[mt][1], 0, 0, 0);
            }
        __syncthreads();   // all LDS frag reads done (gbuf aliases As1)

        // ---- gates to LDS: C layout row=(lane>>4)*4+r, col=lane&15 ----
        int r0 = (lane >> 4) * 4, ccol = lane15;
#pragma unroll
        for (int mt = 0; mt < 2; mt++)
#pragma unroll
            for (int nt = 0; nt < 2; nt++)
#pragma unroll
                for (int r = 0; r < 4; r++)
                    gbuf[wv * 1056 + (mt * 16 + r0 + r) * 33 + nt * 16 + ccol] = acc[mt][nt][r];
        __syncthreads();

        // ---- cell update + coherent h store ----
        union { ull u; __hip_bfloat16 h[4]; } pk;
#pragma unroll
        for (int jj = 0; jj < 4; jj++) {
            float gi = gbuf[0 * 1056 + m * 33 + d0 + jj] + bb[0][jj];
            float gf = gbuf[1 * 1056 + m * 33 + d0 + jj] + bb[1][jj];
            float gg = gbuf[2 * 1056 + m * 33 + d0 + jj] + bb[2][jj];
            float go = gbuf[3 * 1056 + m * 33 + d0 + jj] + bb[3][jj];
            float c = fsig(gf) * cst[jj] + fsig(gi) * ftanh(gg);
            cst[jj] = c;
            pk.h[jj] = __float2bfloat16(fsig(go) * ftanh(c));
        }
        cstore(reinterpret_cast<ull*>(Hown + (size_t)(t + 1) * 98304 +
                                      (size_t)(g * 32 + m) * 384 + dgl),
               pk.u);

        __syncthreads();   // drains vmcnt(0): all h stores acked at L3
        if (tid == 0)
            __hip_atomic_fetch_add(own, 1u, __ATOMIC_RELAXED, AGT);
    }
}

__global__ __launch_bounds__(256, 1) void lstm_persistent(
    const __hip_bfloat16* __restrict__ Xb,
    const __hip_bfloat16* __restrict__ Wcat0,
    const __hip_bfloat16* __restrict__ Wcat1,
    const float* __restrict__ bih0, const float* __restrict__ bhh0,
    const float* __restrict__ bih1, const float* __restrict__ bhh1,
    __hip_bfloat16* __restrict__ H0, __hip_bfloat16* __restrict__ H1,
    unsigned* __restrict__ bar)
{
    __shared__ __align__(16) char smem[49664];
    short* As1 = (short*)smem;             // 24832 B
    short* As2 = (short*)(smem + 24832);   // 24832 B
    float* gbuf = (float*)smem;            // 16896 B, aliases As1 (phase-disjoint)

    int tid = threadIdx.x;
    int c = blockIdx.x & 15;
    int l = c & 1, g = c >> 1;
    int bsub = blockIdx.x >> 4;
    unsigned* own = bar + c * 64;
    unsigned* prod = bar + (c ^ 1) * 64;   // layer1's producer = layer0 chain

    if (l == 0)
        run_chain<0>(Xb, Wcat0, bih0, bhh0, nullptr, H0, own, nullptr,
                     As1, As2, gbuf, g, bsub, tid);
    else
        run_chain<1>(nullptr, Wcat1, bih1, bhh1, H0, H1, own, prod,
                     As1, As2, gbuf, g, bsub, tid);
}

// ---------------- emissions: EM (65536,10) = H1 (65536,384) @ Weff^T + beff ----------------
__global__ __launch_bounds__(256) void em_kernel(const __hip_bfloat16* __restrict__ H1,
                                                 const float* __restrict__ Weff,
                                                 const float* __restrict__ beff,
                                                 float* __restrict__ em) {
    __shared__ __hip_bfloat16 At[256 * 68];
    __shared__ float Wt[640];
    __shared__ float bf[10];
    int tid = threadIdx.x;
    int row0 = blockIdx.x * 256;
    if (tid < 10) bf[tid] = beff[tid];
    float acc[10];
#pragma unroll
    for (int j = 0; j < 10; j++) acc[j] = 0.f;

    for (int kt = 0; kt < 384; kt += 64) {
        __syncthreads();
#pragma unroll
        for (int q = 0; q < 16; q++) {
            int flat = q * 256 + tid;
            int r = flat >> 4;
            int k4 = flat & 15;
            const __hip_bfloat16* src = H1 + (size_t)(row0 + r) * 384 + kt + k4 * 4;
            *reinterpret_cast<uint2*>(&At[r * 68 + k4 * 4]) =
                *reinterpret_cast<const uint2*>(src);
        }
        for (int q = tid; q < 640; q += 256) {
            int j = q >> 6, k = q & 63;
            Wt[q] = Weff[j * 384 + kt + k];
        }
        __syncthreads();
        for (int k = 0; k < 64; k++) {
            float a = __bfloat162float(At[tid * 68 + k]);
#pragma unroll
            for (int j = 0; j < 10; j++) acc[j] += a * Wt[j * 64 + k];
        }
    }
#pragma unroll
    for (int j = 0; j < 10; j++) em[(size_t)(row0 + tid) * 10 + j] = acc[j] + bf[j];
}

// ---------------- CRF: one block (64 thr) per sequence ----------------
__global__ __launch_bounds__(64) void crf_kernel(const float* __restrict__ em,
                                                 const int* __restrict__ tags,
                                                 const float* __restrict__ start_t,
                                                 const float* __restrict__ end_t,
                                                 const float* __restrict__ trans,
                                                 float* __restrict__ nll) {
    int s = blockIdx.x;
    int l = threadIdx.x;
    __shared__ float tr[100];
    __shared__ float aA[16], aB[16];
    if (l < 100) tr[l] = trans[l];
    if (l < 36)  tr[l + 64] = trans[l + 64];
    __syncthreads();

    float part = 0.f;
    for (int b = l; b < 256; b += 64) {
        int tg = tags[s * 256 + b];
        part += em[(size_t)(s * 256 + b) * 10 + tg];
        if (b > 0) {
            int tp = tags[s * 256 + b - 1];
            part += tr[tp * 10 + tg];
        }
    }
    for (int off = 32; off > 0; off >>= 1) part += __shfl_down(part, off);

    if (l < 10) aA[l] = start_t[l] + em[(size_t)(s * 256) * 10 + l];
    __syncthreads();
    for (int b = 1; b < 256; b++) {
        const float* rb = (b & 1) ? aA : aB;
        float* wb = (b & 1) ? aB : aA;
        if (l < 10) {
            float m = -1e30f;
            for (int i = 0; i < 10; i++) m = fmaxf(m, rb[i] + tr[i * 10 + l]);
            float ssum = 0.f;
            for (int i = 0; i < 10; i++) ssum += __expf(rb[i] + tr[i * 10 + l] - m);
            wb[l] = em[(size_t)(s * 256 + b) * 10 + l] + m + __logf(ssum);
        }
        __syncthreads();
    }
    if (l == 0) {
        const float* af = aB;
        float m = -1e30f;
        for (int i = 0; i < 10; i++) m = fmaxf(m, af[i] + end_t[i]);
        float ssum = 0.f;
        for (int i = 0; i < 10; i++) ssum += __expf(af[i] + end_t[i] - m);
        float logZ = m + __logf(ssum);
        float score = part + start_t[tags[s * 256]] + end_t[tags[s * 256 + 255]];
        nll[s] = logZ - score;
    }
}

__global__ __launch_bounds__(256) void reduce_k(const float* __restrict__ nll,
                                                float* __restrict__ out) {
    __shared__ float sm[256];
    int t = threadIdx.x;
    sm[t] = nll[t];
    __syncthreads();
    for (int s = 128; s > 0; s >>= 1) {
        if (t < s) sm[t] += sm[t + s];
        __syncthreads();
    }
    if (t == 0) out[0] = sm[0];
}

// ---------------- host ----------------

extern "C" void kernel_launch(void* const* d_in, const int* in_sizes, int n_in,
                              void* d_out, int out_size, void* d_ws, size_t ws_size,
                              hipStream_t stream) {
    const float* x     = (const float*)d_in[0];
    const int*   tags  = (const int*)d_in[2];
    const float* Wih0  = (const float*)d_in[3];
    const float* Whh0  = (const float*)d_in[4];
    const float* bih0  = (const float*)d_in[5];
    const float* bhh0  = (const float*)d_in[6];
    const float* Wih1  = (const float*)d_in[7];
    const float* Whh1  = (const float*)d_in[8];
    const float* bih1  = (const float*)d_in[9];
    const float* bhh1  = (const float*)d_in[10];
    const float* W1    = (const float*)d_in[11];
    const float* b1    = (const float*)d_in[12];
    const float* W2    = (const float*)d_in[13];
    const float* b2    = (const float*)d_in[14];
    const float* W3    = (const float*)d_in[15];
    const float* b3    = (const float*)d_in[16];
    const float* start_t = (const float*)d_in[17];
    const float* end_t   = (const float*)d_in[18];
    const float* trans   = (const float*)d_in[19];

    char* ws = (char*)d_ws;
    size_t off = 0;
    auto alloc = [&](size_t bytes) { void* p = ws + off; off += (bytes + 255) & ~(size_t)255; return p; };

    __hip_bfloat16* Xb    = (__hip_bfloat16*)alloc((size_t)65536 * 128 * 2);
    __hip_bfloat16* Wcat0 = (__hip_bfloat16*)alloc((size_t)1536 * 512 * 2);
    __hip_bfloat16* Wcat1 = (__hip_bfloat16*)alloc((size_t)1536 * 768 * 2);
    __hip_bfloat16* H0b   = (__hip_bfloat16*)alloc((size_t)257 * 98304 * 2);
    __hip_bfloat16* H1b   = (__hip_bfloat16*)alloc((size_t)257 * 98304 * 2);
    float* EM   = (float*)alloc((size_t)65536 * 10 * 4);
    float* Wtmp = (float*)alloc((size_t)10 * 512 * 4);
    float* Weff = (float*)alloc((size_t)10 * 384 * 4);
    float* beff = (float*)alloc(256);
    float* nll  = (float*)alloc(256 * 4);
    unsigned* bar = (unsigned*)alloc(1024 * 4);

    // prep
    prep_x<<<32768, 256, 0, stream>>>(x, Xb);
    prep_wcat<<<dim3(2, 1536), 256, 0, stream>>>(Wih0, 100, 128, Whh0, Wcat0, 512);
    prep_wcat<<<dim3(3, 1536), 256, 0, stream>>>(Wih1, 384, 384, Whh1, Wcat1, 768);
    init_zero<<<384, 256, 0, stream>>>(H0b, H1b, bar);
    wtmp_k<<<20, 256, 0, stream>>>(W3, W2, Wtmp);
    weff_k<<<15, 256, 0, stream>>>(Wtmp, W1, Weff);
    beff_k<<<1, 64, 0, stream>>>(W3, b2, Wtmp, b1, b3, beff);

    // both LSTM layers, pipelined, one persistent kernel
    lstm_persistent<<<192, 256, 0, stream>>>(Xb, Wcat0, Wcat1,
                                             bih0, bhh0, bih1, bhh1,
                                             H0b, H1b, bar);

    // emissions + CRF
    em_kernel<<<256, 256, 0, stream>>>(H1b + 98304, Weff, beff, EM);
    crf_kernel<<<256, 64, 0, stream>>>(EM, tags, start_t, end_t, trans, nll);
    reduce_k<<<1, 256, 0, stream>>>(nll, (float*)d_out);
}